// Round 4
// baseline (600.109 us; speedup 1.0000x reference)
//
#include <hip/hip_runtime.h>

// Sparse average pooling: out[ro[r], c] += in[ri[r], c] / 8, C=64 fp32.
//
// Round-5b: Little's-law round (round-5 with the NT-load type fix:
// __builtin_nontemporal_load needs ext_vector_type, not HIP int4).
//  - build: 2 rules/thread -> ~45 waves/CU demand, 2 RMWs in flight.
//  - gather: 2 output rows per thread (p and p+n_out/2) -> 14 independent
//    feature loads in flight per thread; wave demand still ~180/CU.
//  - bucket header lines single-use -> nontemporal loads; NT output stores.
//  - bucket row = 64B line = [count, e0..e14]; ws zeroed so dead slots hold
//    index 0 (valid row, L1-hot broadcast); adds predicated by float masks.
//    k>7 tail (5% at lambda=4) stays branchy. Overflow -> pair list.

#define C_CHANNELS 64
#define ROW_INTS 16       // 64 B bucket row
#define CAP_ENT 15        // entries per bucket row (slot 0 is the count)
#define OVF_CAP 16384

typedef float f32x4 __attribute__((ext_vector_type(4)));
typedef int   i32x4 __attribute__((ext_vector_type(4)));

__global__ __launch_bounds__(256) void
zero_ws_kernel(int4* __restrict__ p, int n4, int* __restrict__ ovf_cnt) {
    int i = blockIdx.x * blockDim.x + threadIdx.x;
    int stride = gridDim.x * blockDim.x;
    int4 z = make_int4(0, 0, 0, 0);
    for (; i < n4; i += stride) p[i] = z;
    if (blockIdx.x == 0 && threadIdx.x == 0) *ovf_cnt = 0;
}

__device__ __forceinline__ void
store_entry(int* __restrict__ row, int pos, int ri,
            int ro, int* __restrict__ ovf_cnt, int2* __restrict__ ovf_pairs) {
    if (pos < CAP_ENT) {
        row[1 + pos] = ri;
    } else {
        int oi = atomicAdd(ovf_cnt, 1);
        if (oi < OVF_CAP) ovf_pairs[oi] = make_int2(ri, ro);
    }
}

__global__ __launch_bounds__(256) void
build_kernel(const int* __restrict__ rules_in,
             const int* __restrict__ rules_out,
             int* __restrict__ bucket,
             int* __restrict__ ovf_cnt,
             int2* __restrict__ ovf_pairs,
             int n_rules) {
    int t = blockIdx.x * blockDim.x + threadIdx.x;
    int r0 = t << 1;
    if (r0 >= n_rules) return;
    if (r0 + 2 <= n_rules) {
        int2 ri2 = *reinterpret_cast<const int2*>(rules_in + r0);
        int2 ro2 = *reinterpret_cast<const int2*>(rules_out + r0);
        int* pa = bucket + (size_t)ro2.x * ROW_INTS;
        int* pb = bucket + (size_t)ro2.y * ROW_INTS;
        int sa = atomicAdd(pa, 1);      // both RMWs in flight before
        int sb = atomicAdd(pb, 1);      // either dependent store
        store_entry(pa, sa, ri2.x, ro2.x, ovf_cnt, ovf_pairs);
        store_entry(pb, sb, ri2.y, ro2.y, ovf_cnt, ovf_pairs);
    } else {
        int ro = rules_out[r0];
        int* row = bucket + (size_t)ro * ROW_INTS;
        int pos = atomicAdd(row, 1);
        store_entry(row, pos, rules_in[r0], ro, ovf_cnt, ovf_pairs);
    }
}

__global__ __launch_bounds__(256) void
gather_kernel(const float* __restrict__ in,
              const int* __restrict__ bucket,
              float* __restrict__ out,
              int n_out) {
    int idx = blockIdx.x * blockDim.x + threadIdx.x;
    int pair = idx >> 4;          // 16 lanes per output row
    int c4 = (idx & 15) << 2;     // 4 channels per lane
    int half = (n_out + 1) >> 1;
    if (pair >= half) return;

    int roA = pair;
    int roB = pair + half;
    bool hasB = roB < n_out;
    int roBs = hasB ? roB : roA;  // safe alias when odd n_out

    const i32x4* rowA = reinterpret_cast<const i32x4*>(bucket + (size_t)roA * ROW_INTS);
    const i32x4* rowB = reinterpret_cast<const i32x4*>(bucket + (size_t)roBs * ROW_INTS);
    // Single-use header lines: nontemporal.
    i32x4 a0 = __builtin_nontemporal_load(&rowA[0]);
    i32x4 a1 = __builtin_nontemporal_load(&rowA[1]);
    i32x4 b0 = __builtin_nontemporal_load(&rowB[0]);
    i32x4 b1 = __builtin_nontemporal_load(&rowB[1]);
    int kA = a0.x < CAP_ENT ? a0.x : CAP_ENT;
    int kB = b0.x < CAP_ENT ? b0.x : CAP_ENT;

    const float* base = in + c4;
#define LDV(r) (*reinterpret_cast<const f32x4*>(base + (size_t)(unsigned)(r) * C_CHANNELS))

    // 14 independent feature loads in flight (dead slots hold 0 -> row 0,
    // L1-hot broadcast). Adds predicated by float masks.
    f32x4 va0 = LDV(a0.y);
    f32x4 va1 = LDV(a0.z);
    f32x4 va2 = LDV(a0.w);
    f32x4 va3 = LDV(a1.x);
    f32x4 va4 = LDV(a1.y);
    f32x4 va5 = LDV(a1.z);
    f32x4 va6 = LDV(a1.w);
    f32x4 vb0 = LDV(b0.y);
    f32x4 vb1 = LDV(b0.z);
    f32x4 vb2 = LDV(b0.w);
    f32x4 vb3 = LDV(b1.x);
    f32x4 vb4 = LDV(b1.y);
    f32x4 vb5 = LDV(b1.z);
    f32x4 vb6 = LDV(b1.w);

    f32x4 sA = va0 * (kA > 0 ? 1.f : 0.f);
    sA += va1 * (kA > 1 ? 1.f : 0.f);
    sA += va2 * (kA > 2 ? 1.f : 0.f);
    sA += va3 * (kA > 3 ? 1.f : 0.f);
    sA += va4 * (kA > 4 ? 1.f : 0.f);
    sA += va5 * (kA > 5 ? 1.f : 0.f);
    sA += va6 * (kA > 6 ? 1.f : 0.f);

    f32x4 sB = vb0 * (kB > 0 ? 1.f : 0.f);
    sB += vb1 * (kB > 1 ? 1.f : 0.f);
    sB += vb2 * (kB > 2 ? 1.f : 0.f);
    sB += vb3 * (kB > 3 ? 1.f : 0.f);
    sB += vb4 * (kB > 4 ? 1.f : 0.f);
    sB += vb5 * (kB > 5 ? 1.f : 0.f);
    sB += vb6 * (kB > 6 ? 1.f : 0.f);

    if (kA > 7) {               // ~5% of rows at lambda=4
        i32x4 a2 = __builtin_nontemporal_load(&rowA[2]);
        i32x4 a3 = __builtin_nontemporal_load(&rowA[3]);
        f32x4 w0 = LDV(a2.x);
        f32x4 w1 = LDV(a2.y);
        f32x4 w2 = LDV(a2.z);
        f32x4 w3 = LDV(a2.w);
        f32x4 w4 = LDV(a3.x);
        f32x4 w5 = LDV(a3.y);
        f32x4 w6 = LDV(a3.z);
        f32x4 w7 = LDV(a3.w);
        sA += w0;
        sA += w1 * (kA > 8  ? 1.f : 0.f);
        sA += w2 * (kA > 9  ? 1.f : 0.f);
        sA += w3 * (kA > 10 ? 1.f : 0.f);
        sA += w4 * (kA > 11 ? 1.f : 0.f);
        sA += w5 * (kA > 12 ? 1.f : 0.f);
        sA += w6 * (kA > 13 ? 1.f : 0.f);
        sA += w7 * (kA > 14 ? 1.f : 0.f);
    }
    if (kB > 7) {
        i32x4 b2 = __builtin_nontemporal_load(&rowB[2]);
        i32x4 b3 = __builtin_nontemporal_load(&rowB[3]);
        f32x4 w0 = LDV(b2.x);
        f32x4 w1 = LDV(b2.y);
        f32x4 w2 = LDV(b2.z);
        f32x4 w3 = LDV(b2.w);
        f32x4 w4 = LDV(b3.x);
        f32x4 w5 = LDV(b3.y);
        f32x4 w6 = LDV(b3.z);
        f32x4 w7 = LDV(b3.w);
        sB += w0;
        sB += w1 * (kB > 8  ? 1.f : 0.f);
        sB += w2 * (kB > 9  ? 1.f : 0.f);
        sB += w3 * (kB > 10 ? 1.f : 0.f);
        sB += w4 * (kB > 11 ? 1.f : 0.f);
        sB += w5 * (kB > 12 ? 1.f : 0.f);
        sB += w6 * (kB > 13 ? 1.f : 0.f);
        sB += w7 * (kB > 14 ? 1.f : 0.f);
    }
#undef LDV

    f32x4 oA = sA * 0.125f;
    __builtin_nontemporal_store(
        oA, reinterpret_cast<f32x4*>(out + (size_t)roA * C_CHANNELS + c4));
    if (hasB) {
        f32x4 oB = sB * 0.125f;
        __builtin_nontemporal_store(
            oB, reinterpret_cast<f32x4*>(out + (size_t)roB * C_CHANNELS + c4));
    }
}

__global__ __launch_bounds__(256) void
ovf_scatter_kernel(const float* __restrict__ in,
                   const int* __restrict__ ovf_cnt,
                   const int2* __restrict__ ovf_pairs,
                   float* __restrict__ out) {
    int n = *ovf_cnt;
    if (n > OVF_CAP) n = OVF_CAP;
    int total = n * 16;
    int stride = gridDim.x * blockDim.x;
    for (int idx = blockIdx.x * blockDim.x + threadIdx.x; idx < total; idx += stride) {
        int p  = idx >> 4;
        int c4 = (idx & 15) << 2;
        int2 pr = ovf_pairs[p];
        const float4 v = *reinterpret_cast<const float4*>(
            in + (size_t)pr.x * C_CHANNELS + c4);
        float* o = out + (size_t)pr.y * C_CHANNELS + c4;
        atomicAdd(o + 0, v.x * 0.125f);
        atomicAdd(o + 1, v.y * 0.125f);
        atomicAdd(o + 2, v.z * 0.125f);
        atomicAdd(o + 3, v.w * 0.125f);
    }
}

// ---- Fallback (ws too small): scatter-atomic path ----
__global__ __launch_bounds__(256) void
zero4_kernel(float4* __restrict__ p, long n4) {
    long i = (long)blockIdx.x * blockDim.x + threadIdx.x;
    long stride = (long)gridDim.x * blockDim.x;
    float4 z = {0.f, 0.f, 0.f, 0.f};
    for (; i < n4; i += stride) p[i] = z;
}

__global__ __launch_bounds__(256) void
avgpool_scatter_kernel(const float* __restrict__ in,
                       const int* __restrict__ rules_in,
                       const int* __restrict__ rules_out,
                       float* __restrict__ out,
                       int n_rules) {
    int idx = blockIdx.x * blockDim.x + threadIdx.x;
    int rule = idx >> 4;
    int c4   = (idx & 15) << 2;
    if (rule >= n_rules) return;
    int ri = rules_in[rule];
    int ro = rules_out[rule];
    const float4 v = *reinterpret_cast<const float4*>(
        in + (size_t)ri * C_CHANNELS + c4);
    float* o = out + (size_t)ro * C_CHANNELS + c4;
    atomicAdd(o + 0, v.x * 0.125f);
    atomicAdd(o + 1, v.y * 0.125f);
    atomicAdd(o + 2, v.z * 0.125f);
    atomicAdd(o + 3, v.w * 0.125f);
}

extern "C" void kernel_launch(void* const* d_in, const int* in_sizes, int n_in,
                              void* d_out, int out_size, void* d_ws, size_t ws_size,
                              hipStream_t stream) {
    const float* in        = (const float*)d_in[0];
    const int*   rules_in  = (const int*)d_in[1];
    const int*   rules_out = (const int*)d_in[2];
    float*       out       = (float*)d_out;

    const int n_rules = in_sizes[1];            // 1,500,000
    const int n_out   = out_size / C_CHANNELS;  // 375,000

    // Workspace layout (16B-aligned):
    //   [bucket: n_out * 16 ints (64B rows)][ovf_cnt: 16B][ovf_pairs: OVF_CAP int2]
    size_t list_bytes = (size_t)n_out * ROW_INTS * sizeof(int);   // 24 MB
    size_t list_pad   = (list_bytes + 15) & ~(size_t)15;
    size_t ovf_hdr    = 16;
    size_t need = list_pad + ovf_hdr + (size_t)OVF_CAP * sizeof(int2);

    const int block = 256;

    if (ws_size < need) {
        // Fallback: zero out, then scatter atomics.
        long n4 = (long)out_size / 4;
        int grid = (int)((n4 + block - 1) / block);
        if (grid > 65535) grid = 65535;
        zero4_kernel<<<grid, block, 0, stream>>>((float4*)out, n4);
        int total = n_rules * 16;
        avgpool_scatter_kernel<<<(total + block - 1) / block, block, 0, stream>>>(
            in, rules_in, rules_out, out, n_rules);
        return;
    }

    int*  bucket    = (int*)d_ws;
    int*  ovf_cnt   = (int*)((char*)d_ws + list_pad);
    int2* ovf_pairs = (int2*)((char*)d_ws + list_pad + ovf_hdr);

    // Pass 0: zero bucket rows (24 MB dense) + overflow counter.
    {
        int n4 = (int)(list_bytes / 16);   // n_out * 4 int4s
        int grid = (n4 + block - 1) / block;
        zero_ws_kernel<<<grid, block, 0, stream>>>((int4*)bucket, n4, ovf_cnt);
    }

    // Pass 1: build bucket rows (2 rules/thread -> ~45 waves/CU demand).
    {
        int threads = (n_rules + 1) / 2;
        build_kernel<<<(threads + block - 1) / block, block, 0, stream>>>(
            rules_in, rules_out, bucket, ovf_cnt, ovf_pairs, n_rules);
    }

    // Pass 2: gather, 2 output rows/thread (14 loads in flight), NT store.
    {
        long half = (n_out + 1) >> 1;
        long total = half * 16;
        int grid = (int)((total + block - 1) / block);
        gather_kernel<<<grid, block, 0, stream>>>(in, bucket, out, n_out);
    }

    // Pass 3: merge deferred overflow contributions (usually 0 pairs).
    ovf_scatter_kernel<<<64, block, 0, stream>>>(in, ovf_cnt, ovf_pairs, out);
}